// Round 1
// baseline (11480.310 us; speedup 1.0000x reference)
//
#include <hip/hip_runtime.h>

// EncoderPlanarLSTM: T=256,B=1024,DX=48,DA=16 (I=64), H=512, Z=32, F=4
// out = [mu(1024x32) | log_var(1024x32) | u(1024x128) | w(1024x128) | b(1024x4)] fp32

typedef __attribute__((__ext_vector_type__(8))) short bx8;   // 8 bf16 (4 VGPR)
typedef __attribute__((__ext_vector_type__(4))) float fx4;

#define NSTEP 256
#define NKT   18          // K-tiles of 32 over K=576 (512 h + 64 y)
#define ROWB  1152        // bytes per A row in LDS (576*2)

__device__ __forceinline__ short bf16_of(float f) {
  union { float f; unsigned u; } c; c.f = f;
  unsigned r = c.u + 0x7fffu + ((c.u >> 16) & 1u);   // RNE
  return (short)(r >> 16);
}
__device__ __forceinline__ float fsigmoid(float x) {
  float e = __builtin_amdgcn_exp2f(-1.44269504f * x);
  return __builtin_amdgcn_rcpf(1.0f + e);
}
__device__ __forceinline__ float ftanh_(float x) {
  float e = __builtin_amdgcn_exp2f(2.88539008f * x);
  return 1.0f - 2.0f * __builtin_amdgcn_rcpf(1.0f + e);
}

// ---------------- pack masked+concat input to bf16, natural time order ----------------
__global__ __launch_bounds__(256) void pack_y_kernel(
    const float* __restrict__ x, const float* __restrict__ a,
    const float* __restrict__ mk, short* __restrict__ y) {
  const int idx = blockIdx.x * 256 + threadIdx.x;      // t*1024 + b, < 262144
  const float* xp = x + (size_t)idx * 48;
  const float* mp = mk + (size_t)idx * 48;
  const float* ap = a + (size_t)idx * 16;
  short* yp = y + (size_t)idx * 64;
  float v[64];
#pragma unroll
  for (int j = 0; j < 12; ++j) {
    fx4 xv = *(const fx4*)(xp + j * 4);
    fx4 mv = *(const fx4*)(mp + j * 4);
#pragma unroll
    for (int t = 0; t < 4; ++t) v[j * 4 + t] = xv[t] * mv[t];
  }
#pragma unroll
  for (int j = 0; j < 4; ++j) {
    fx4 av = *(const fx4*)(ap + j * 4);
#pragma unroll
    for (int t = 0; t < 4; ++t) v[48 + j * 4 + t] = av[t];
  }
#pragma unroll
  for (int c = 0; c < 8; ++c) {
    bx8 o;
#pragma unroll
    for (int t = 0; t < 8; ++t) o[t] = bf16_of(v[c * 8 + t]);
    *(bx8*)(yp + c * 8) = o;
  }
}

// ---------------- recurrent LSTM, weight-stationary in VGPRs ----------------
// grid 256 WGs x 256 thr. WG(gb=wg&15, gn=wg>>4): batch rows gb*64..+64, hcols gn*32..+32.
// waves: bh=wave>>1 (batch half of 32 rows), hh=wave&1 (hcol half of 16).
// Per-wave resident B: 4 gates x 18 k-tiles of bf16 W rows (cols n-major) = 288 VGPR.
__global__ __launch_bounds__(256, 1) void lstm_rec(
    const short* __restrict__ yw,      // [256][1024][64] bf16
    const float* __restrict__ w_hh,    // [2048][512]
    const float* __restrict__ w_ih,    // [2048][64]
    const float* __restrict__ b_ih, const float* __restrict__ b_hh,
    short* hbuf,                       // [2][1024][512] bf16
    float* __restrict__ hfinal,        // [1024][512]
    unsigned* ctr)                     // [16] stride-32 u32 group barriers
{
  // >81920B forces exactly 1 WG/CU regardless of VGPR choice (spin-barrier safety)
  __shared__ __align__(16) char Ash[64 * ROWB + 8448];
  const int tid = threadIdx.x;
  const int wg  = blockIdx.x;
  const int gb  = wg & 15;
  const int gn  = wg >> 4;
  const int wv  = tid >> 6;
  const int lane = tid & 63;
  const int l15 = lane & 15;
  const int l4  = lane >> 4;
  const int bh  = wv >> 1;
  const int hh  = wv & 1;

  // ---- load resident B fragments (one-time) ----
  bx8 Bf[4 * NKT];
  float bias[4];
#pragma unroll
  for (int nt = 0; nt < 4; ++nt) {
    const int col = nt * 512 + gn * 32 + hh * 16 + l15;   // gate col in [0,2048)
    bias[nt] = b_ih[col] + b_hh[col];
#pragma unroll
    for (int kt = 0; kt < NKT; ++kt) {
      const int k0 = kt * 32 + l4 * 8;
      const float* src = (k0 < 512) ? (w_hh + (size_t)col * 512 + k0)
                                    : (w_ih + (size_t)col * 64 + (k0 - 512));
      fx4 w0 = *(const fx4*)(src);
      fx4 w1 = *(const fx4*)(src + 4);
      bx8 b;
#pragma unroll
      for (int t = 0; t < 4; ++t) { b[t] = bf16_of(w0[t]); b[4 + t] = bf16_of(w1[t]); }
      Bf[nt * NKT + kt] = b;
    }
  }

  float cst[8];
#pragma unroll
  for (int i = 0; i < 8; ++i) cst[i] = 0.f;

  const int row0 = bh * 32 + l15;           // A-frag row for m=0 (m=1 adds 16; same &7)
  const unsigned xm = (unsigned)((row0 & 7) << 4);
  const int aoff0 = row0 * ROWB;
  const int koff  = l4 * 16;
  const int colh  = gn * 32 + hh * 16 + l15;
  unsigned* cp = ctr + gb * 32;

#pragma unroll 1
  for (int s = 0; s < NSTEP; ++s) {
    const short* hprev = hbuf + (size_t)(s & 1) * (1024 * 512);
    short* hnext = hbuf + (size_t)((s + 1) & 1) * (1024 * 512);
    const short* ysl = yw + (size_t)(255 - s) * (1024 * 64);

    // ---- stage A = [h | y] (64 rows x 576 bf16) with source-side XOR swizzle ----
#pragma unroll
    for (int it = 0; it < 18; ++it) {
      const unsigned G = it * 256 + tid;            // granule 0..4607
      const unsigned row = G / 72u;
      const unsigned gg = G % 72u;
      const unsigned kb = (gg ^ (row & 7u)) << 4;   // logical k-byte
      const char* src;
      if (kb < 1024u)
        src = (const char*)(hprev + ((size_t)gb * 64 + row) * 512) + kb;
      else
        src = (const char*)(ysl + ((size_t)gb * 64 + row) * 64) + (kb - 1024u);
      char* dst = Ash + it * 4096 + (tid & 192) * 16;   // wave-uniform base; HW adds lane*16
      __builtin_amdgcn_global_load_lds(
          (const __attribute__((address_space(1))) unsigned*)src,
          (__attribute__((address_space(3))) unsigned*)dst, 16, 0, 0);
    }
    __syncthreads();   // drains vmcnt (global_load_lds) per barrier semantics

    // ---- GEMM: acc[m][gate] += A(h|y) x W^T, B resident ----
    fx4 acc[8];
#pragma unroll
    for (int m = 0; m < 2; ++m)
#pragma unroll
      for (int nt = 0; nt < 4; ++nt) {
        fx4 z = {bias[nt], bias[nt], bias[nt], bias[nt]};
        acc[m * 4 + nt] = z;
      }
#pragma unroll
    for (int kt = 0; kt < NKT; ++kt) {
      const unsigned ko = (unsigned)(kt * 64 + koff);
      bx8 A0 = *(const bx8*)(Ash + aoff0 + (int)(ko ^ xm));
      bx8 A1 = *(const bx8*)(Ash + aoff0 + 16 * ROWB + (int)(ko ^ xm));
#pragma unroll
      for (int nt = 0; nt < 4; ++nt) {
        acc[nt]     = __builtin_amdgcn_mfma_f32_16x16x32_bf16(A0, Bf[nt * NKT + kt], acc[nt], 0, 0, 0);
        acc[4 + nt] = __builtin_amdgcn_mfma_f32_16x16x32_bf16(A1, Bf[nt * NKT + kt], acc[4 + nt], 0, 0, 0);
      }
    }

    // ---- gates, c/h update, publish h ----
#pragma unroll
    for (int m = 0; m < 2; ++m) {
#pragma unroll
      for (int r = 0; r < 4; ++r) {
        const int rowg = gb * 64 + bh * 32 + m * 16 + l4 * 4 + r;
        float gi = acc[m * 4 + 0][r];
        float gf = acc[m * 4 + 1][r];
        float gg = acc[m * 4 + 2][r];
        float go = acc[m * 4 + 3][r];
        float c = fsigmoid(gf) * cst[m * 4 + r] + fsigmoid(gi) * ftanh_(gg);
        cst[m * 4 + r] = c;
        float h = fsigmoid(go) * ftanh_(c);
        hnext[(size_t)rowg * 512 + colh] = bf16_of(h);
        if (s == NSTEP - 1) hfinal[(size_t)rowg * 512 + colh] = h;
      }
    }

    // ---- 16-WG batch-group barrier ----
    if (s < NSTEP - 1) {
      __threadfence();          // release: write back dirty L2 (agent scope)
      __syncthreads();
      if (tid == 0) {
        __hip_atomic_fetch_add(cp, 1u, __ATOMIC_RELEASE, __HIP_MEMORY_SCOPE_AGENT);
        const unsigned tgt = 16u * (unsigned)(s + 1);
        unsigned guard = 0;
        while (__hip_atomic_load(cp, __ATOMIC_RELAXED, __HIP_MEMORY_SCOPE_AGENT) < tgt &&
               ++guard < (1u << 30)) {
          __builtin_amdgcn_s_sleep(1);
        }
      }
      __syncthreads();
      __threadfence();          // acquire: invalidate stale caches before next stage
    }
  }
}

// ---------------- heads: exact fp32 VALU GEMM [1024 x 324 x 512] + epilogue ----------------
__global__ __launch_bounds__(256) void heads_kernel(
    const float* __restrict__ hf,
    const float* __restrict__ lin_w, const float* __restrict__ lin_b,
    const float* __restrict__ lv_w,  const float* __restrict__ lv_b,
    const float* __restrict__ u_w,   const float* __restrict__ u_b,
    const float* __restrict__ ww_w,  const float* __restrict__ ww_b,
    const float* __restrict__ bf_w,  const float* __restrict__ bf_b,
    float* __restrict__ out)
{
  __shared__ float hs[64 * 513];
  const int tid = threadIdx.x;
  const int gb = blockIdx.x;     // 0..15
  const int cg = blockIdx.y;     // 0..5, 54 cols each
  for (int i = tid; i < 8192; i += 256) {          // 8192 float4 = 64x512
    fx4 v = *(const fx4*)(hf + (size_t)gb * 32768 + (size_t)i * 4);
    const int row = i >> 7;          // (i*4)>>9
    const int k = (i * 4) & 511;
    float* d = hs + row * 513 + k;
    d[0] = v[0]; d[1] = v[1]; d[2] = v[2]; d[3] = v[3];
  }
  __syncthreads();
  const int r = tid & 63;
  const int cq = tid >> 6;
  const float* hrow = hs + r * 513;
  const int b_ = gb * 64 + r;
#pragma unroll 1
  for (int j = 0; j < 14; ++j) {
    const int cl = cq + 4 * j;
    if (cl >= 54) break;
    const int C = cg * 54 + cl;      // 0..323
    const float* wp; float bv;
    if (C < 32)       { wp = lin_w + (size_t)C * 512;        bv = lin_b[C]; }
    else if (C < 64)  { wp = lv_w + (size_t)(C - 32) * 512;  bv = lv_b[C - 32]; }
    else if (C < 192) { wp = u_w + (size_t)(C - 64) * 512;   bv = u_b[C - 64]; }
    else if (C < 320) { wp = ww_w + (size_t)(C - 192) * 512; bv = ww_b[C - 192]; }
    else              { wp = bf_w + (size_t)(C - 320) * 512; bv = bf_b[C - 320]; }
    float dot = 0.f;
#pragma unroll 8
    for (int k = 0; k < 512; k += 4) {
      fx4 w = *(const fx4*)(wp + k);
      dot += hrow[k] * w[0] + hrow[k + 1] * w[1] + hrow[k + 2] * w[2] + hrow[k + 3] * w[3];
    }
    const float res = bv + dot;
    if (C < 32)       out[(size_t)b_ * 32 + C] = __builtin_amdgcn_exp2f(res * 1.44269504f) * 0.1f;
    else if (C < 64)  out[32768 + (size_t)b_ * 32 + (C - 32)] = res - 5.f;
    else if (C < 192) out[65536 + (size_t)b_ * 128 + (C - 64)] = res;
    else if (C < 320) out[196608 + (size_t)b_ * 128 + (C - 192)] = res;
    else              out[327680 + (size_t)b_ * 4 + (C - 320)] = res;
  }
}

extern "C" void kernel_launch(void* const* d_in, const int* in_sizes, int n_in,
                              void* d_out, int out_size, void* d_ws, size_t ws_size,
                              hipStream_t stream) {
  (void)in_sizes; (void)n_in; (void)out_size; (void)ws_size;
  const float* x     = (const float*)d_in[0];
  const float* a     = (const float*)d_in[1];
  const float* mask  = (const float*)d_in[2];
  const float* w_ih  = (const float*)d_in[3];
  const float* w_hh  = (const float*)d_in[4];
  const float* b_ih  = (const float*)d_in[5];
  const float* b_hh  = (const float*)d_in[6];
  const float* lin_w = (const float*)d_in[7];
  const float* lin_b = (const float*)d_in[8];
  const float* lv_w  = (const float*)d_in[9];
  const float* lv_b  = (const float*)d_in[10];
  const float* u_w   = (const float*)d_in[11];
  const float* u_b   = (const float*)d_in[12];
  const float* ww_w  = (const float*)d_in[13];
  const float* ww_b  = (const float*)d_in[14];
  const float* bf_w  = (const float*)d_in[15];
  const float* bf_b  = (const float*)d_in[16];

  char* ws = (char*)d_ws;
  short* yw       = (short*)(ws);                 // 33,554,432 B: [256][1024][64] bf16
  short* hbuf     = (short*)(ws + 33554432);      //  2,097,152 B: [2][1024][512] bf16
  float* hfinal   = (float*)(ws + 35651584);      //  2,097,152 B
  unsigned* ctr   = (unsigned*)(ws + 37748736);   //      2,048 B

  hipMemsetAsync(hbuf, 0, 1024 * 512 * 2, stream);   // h(0) = 0
  hipMemsetAsync(ctr, 0, 2048, stream);

  pack_y_kernel<<<1024, 256, 0, stream>>>(x, a, mask, yw);
  lstm_rec<<<256, 256, 0, stream>>>(yw, w_hh, w_ih, b_ih, b_hh, hbuf, hfinal, ctr);
  heads_kernel<<<dim3(16, 6), 256, 0, stream>>>(hfinal, lin_w, lin_b, lv_w, lv_b,
                                                u_w, u_b, ww_w, ww_b, bf_w, bf_b,
                                                (float*)d_out);
}

// Round 2
// 1634.203 us; speedup vs baseline: 7.0250x; 7.0250x over previous
//
#include <hip/hip_runtime.h>

// EncoderPlanarLSTM: T=256,B=1024,DX=48,DA=16 (I=64), H=512, Z=32, F=4
// out = [mu(1024x32) | log_var(1024x32) | u(1024x128) | w(1024x128) | b(1024x4)] fp32

typedef __attribute__((__ext_vector_type__(8))) short bx8;   // 8 bf16 (4 VGPR)
typedef __attribute__((__ext_vector_type__(4))) float fx4;
typedef unsigned long long u64;

#define NSTEP 256
#define NKT   18          // K-tiles of 32 over K=576 (512 h + 64 y)
#define ROWB  1168        // padded LDS bytes per A row (1152 data + 16 pad)

__device__ __forceinline__ short bf16_of(float f) {
  union { float f; unsigned u; } c; c.f = f;
  unsigned r = c.u + 0x7fffu + ((c.u >> 16) & 1u);   // RNE
  return (short)(r >> 16);
}
__device__ __forceinline__ float fsigmoid(float x) {
  float e = __builtin_amdgcn_exp2f(-1.44269504f * x);
  return __builtin_amdgcn_rcpf(1.0f + e);
}
__device__ __forceinline__ float ftanh_(float x) {
  float e = __builtin_amdgcn_exp2f(2.88539008f * x);
  return 1.0f - 2.0f * __builtin_amdgcn_rcpf(1.0f + e);
}

// ---------------- pack masked+concat input to bf16, natural time order ----------------
__global__ __launch_bounds__(256) void pack_y_kernel(
    const float* __restrict__ x, const float* __restrict__ a,
    const float* __restrict__ mk, short* __restrict__ y) {
  const int idx = blockIdx.x * 256 + threadIdx.x;      // t*1024 + b, < 262144
  const float* xp = x + (size_t)idx * 48;
  const float* mp = mk + (size_t)idx * 48;
  const float* ap = a + (size_t)idx * 16;
  short* yp = y + (size_t)idx * 64;
  float v[64];
#pragma unroll
  for (int j = 0; j < 12; ++j) {
    fx4 xv = *(const fx4*)(xp + j * 4);
    fx4 mv = *(const fx4*)(mp + j * 4);
#pragma unroll
    for (int t = 0; t < 4; ++t) v[j * 4 + t] = xv[t] * mv[t];
  }
#pragma unroll
  for (int j = 0; j < 4; ++j) {
    fx4 av = *(const fx4*)(ap + j * 4);
#pragma unroll
    for (int t = 0; t < 4; ++t) v[48 + j * 4 + t] = av[t];
  }
#pragma unroll
  for (int c = 0; c < 8; ++c) {
    bx8 o;
#pragma unroll
    for (int t = 0; t < 8; ++t) o[t] = bf16_of(v[c * 8 + t]);
    *(bx8*)(yp + c * 8) = o;
  }
}

// ---------------- recurrent LSTM, weight-stationary in VGPRs ----------------
// grid 256 WGs x 256 thr. WG(gb=wg&15, gn=wg>>4): batch rows gb*64..+64, hcols gn*32..+32.
// h exchange via relaxed AGENT-scope atomics (sc0|sc1: coherent at L3) — no threadfence,
// no buffer_wbl2/buffer_inv, L2 stays warm for y/W.
__global__ __launch_bounds__(256, 1) void lstm_rec(
    const short* __restrict__ yw,      // [256][1024][64] bf16
    const float* __restrict__ w_hh,    // [2048][512]
    const float* __restrict__ w_ih,    // [2048][64]
    const float* __restrict__ b_ih, const float* __restrict__ b_hh,
    short* hbuf,                       // [2][1024][512] bf16
    float* __restrict__ hfinal,        // [1024][512]
    unsigned* ctr)                     // [16] stride-32 u32 group barriers
{
  // >81920B forces exactly 1 WG/CU regardless of VGPR choice (spin-barrier safety)
  __shared__ __align__(16) char Ash[82432];
  const int tid = threadIdx.x;
  const int wg  = blockIdx.x;
  const int gb  = wg & 15;
  const int gn  = wg >> 4;
  const int wv  = tid >> 6;
  const int lane = tid & 63;
  const int l15 = lane & 15;
  const int l4  = lane >> 4;
  const int bh  = wv >> 1;
  const int hh  = wv & 1;

  // ---- load resident B fragments (one-time) ----
  bx8 Bf[4 * NKT];
  float bias[4];
#pragma unroll
  for (int nt = 0; nt < 4; ++nt) {
    const int col = nt * 512 + gn * 32 + hh * 16 + l15;   // gate col in [0,2048)
    bias[nt] = b_ih[col] + b_hh[col];
#pragma unroll
    for (int kt = 0; kt < NKT; ++kt) {
      const int k0 = kt * 32 + l4 * 8;
      const float* src = (k0 < 512) ? (w_hh + (size_t)col * 512 + k0)
                                    : (w_ih + (size_t)col * 64 + (k0 - 512));
      fx4 w0 = *(const fx4*)(src);
      fx4 w1 = *(const fx4*)(src + 4);
      bx8 b;
#pragma unroll
      for (int t = 0; t < 4; ++t) { b[t] = bf16_of(w0[t]); b[4 + t] = bf16_of(w1[t]); }
      Bf[nt * NKT + kt] = b;
    }
  }

  float cst[8];
#pragma unroll
  for (int i = 0; i < 8; ++i) cst[i] = 0.f;

  // staging geometry: thread owns LDS row (tid>>2), 8B part (tid&3), chunks at byte (tid&3)*8 + i*32
  const int srow = tid >> 2;                 // 0..63
  const int part = tid & 3;
  u64* lq = (u64*)(Ash + srow * ROWB) + part;     // lq[i*4] covers all 36 chunks
  const int growbase = gb * 64 + srow;

  // frag geometry
  const int row0 = bh * 32 + l15;
  const int aoff0 = row0 * ROWB;
  const int koff  = l4 * 16;
  const int colh  = gn * 32 + hh * 16 + l15;
  const bool evenl = (lane & 1) == 0;
  unsigned* cp = ctr + gb * 32;

#pragma unroll 1
  for (int s = 0; s < NSTEP; ++s) {
    const short* hprev = hbuf + (size_t)(s & 1) * (1024 * 512);
    unsigned* hnext32 = (unsigned*)(hbuf + (size_t)((s + 1) & 1) * (1024 * 512));
    const short* ysl = yw + (size_t)(255 - s) * (1024 * 64);

    // ---- stage A = [h | y]: 32 coherent 8B h-loads + 4 plain y-loads, then LDS writes ----
    const u64* hq = (const u64*)(hprev + (size_t)growbase * 512) + part;
    const u64* yq = (const u64*)(ysl + (size_t)growbase * 64) + part;
    u64 vb[36];
#pragma unroll
    for (int i = 0; i < 32; ++i)
      vb[i] = __hip_atomic_load(hq + i * 4, __ATOMIC_RELAXED, __HIP_MEMORY_SCOPE_AGENT);
#pragma unroll
    for (int i = 0; i < 4; ++i)
      vb[32 + i] = *(yq + i * 4);
#pragma unroll
    for (int i = 0; i < 36; ++i)
      lq[i * 4] = vb[i];
    __syncthreads();

    // ---- GEMM: acc[m][gate] += A(h|y) x W^T, B resident ----
    fx4 acc[8];
#pragma unroll
    for (int m = 0; m < 2; ++m)
#pragma unroll
      for (int nt = 0; nt < 4; ++nt) {
        fx4 z = {bias[nt], bias[nt], bias[nt], bias[nt]};
        acc[m * 4 + nt] = z;
      }
#pragma unroll
    for (int kt = 0; kt < NKT; ++kt) {
      const int ko = kt * 64 + koff;
      bx8 A0 = *(const bx8*)(Ash + aoff0 + ko);
      bx8 A1 = *(const bx8*)(Ash + aoff0 + 16 * ROWB + ko);
#pragma unroll
      for (int nt = 0; nt < 4; ++nt) {
        acc[nt]     = __builtin_amdgcn_mfma_f32_16x16x32_bf16(A0, Bf[nt * NKT + kt], acc[nt], 0, 0, 0);
        acc[4 + nt] = __builtin_amdgcn_mfma_f32_16x16x32_bf16(A1, Bf[nt * NKT + kt], acc[4 + nt], 0, 0, 0);
      }
    }

    // ---- gates, c/h update ----
    unsigned hb[8];
#pragma unroll
    for (int m = 0; m < 2; ++m) {
#pragma unroll
      for (int r = 0; r < 4; ++r) {
        float gi = acc[m * 4 + 0][r];
        float gf = acc[m * 4 + 1][r];
        float gg = acc[m * 4 + 2][r];
        float go = acc[m * 4 + 3][r];
        float c = fsigmoid(gf) * cst[m * 4 + r] + fsigmoid(gi) * ftanh_(gg);
        cst[m * 4 + r] = c;
        float h = fsigmoid(go) * ftanh_(c);
        hb[m * 4 + r] = (unsigned)(unsigned short)bf16_of(h);
        if (s == NSTEP - 1) {
          const int rowg = gb * 64 + bh * 32 + m * 16 + l4 * 4 + r;
          hfinal[(size_t)rowg * 512 + colh] = h;
        }
      }
    }

    if (s < NSTEP - 1) {
      // ---- publish h: pair-pack via shfl, 4 coherent u32 stores/thread ----
#pragma unroll
      for (int r = 0; r < 4; ++r) {
        unsigned v0 = hb[r];                       // m=0
        unsigned v1 = hb[4 + r];                   // m=1
        unsigned p0 = (unsigned)__shfl_xor((int)v0, 1);
        unsigned p1 = (unsigned)__shfl_xor((int)v1, 1);
        unsigned packed = evenl ? (v0 | (p0 << 16)) : (p1 | (v1 << 16));
        const int m = evenl ? 0 : 1;
        const int rowg = gb * 64 + bh * 32 + m * 16 + l4 * 4 + r;
        __hip_atomic_store(hnext32 + (size_t)rowg * 256 + (colh >> 1), packed,
                           __ATOMIC_RELAXED, __HIP_MEMORY_SCOPE_AGENT);
      }
      asm volatile("s_waitcnt vmcnt(0)" ::: "memory");   // stores visible at L3
      __syncthreads();                                   // all 256 threads drained; Ash reusable

      // ---- 16-WG batch-group barrier (L3 atomics, no fences) ----
      if (tid == 0) {
        __hip_atomic_fetch_add(cp, 1u, __ATOMIC_RELAXED, __HIP_MEMORY_SCOPE_AGENT);
        const unsigned tgt = 16u * (unsigned)(s + 1);
        unsigned guard = 0;
        while (__hip_atomic_load(cp, __ATOMIC_RELAXED, __HIP_MEMORY_SCOPE_AGENT) < tgt &&
               ++guard < (1u << 30)) {
          __builtin_amdgcn_s_sleep(1);
        }
      }
      __syncthreads();
    }
  }
}

// ---------------- heads: exact fp32 VALU GEMM [1024 x 324 x 512] + epilogue ----------------
__global__ __launch_bounds__(256) void heads_kernel(
    const float* __restrict__ hf,
    const float* __restrict__ lin_w, const float* __restrict__ lin_b,
    const float* __restrict__ lv_w,  const float* __restrict__ lv_b,
    const float* __restrict__ u_w,   const float* __restrict__ u_b,
    const float* __restrict__ ww_w,  const float* __restrict__ ww_b,
    const float* __restrict__ bf_w,  const float* __restrict__ bf_b,
    float* __restrict__ out)
{
  __shared__ float hs[64 * 513];
  const int tid = threadIdx.x;
  const int gb = blockIdx.x;     // 0..15
  const int cg = blockIdx.y;     // 0..5, 54 cols each
  for (int i = tid; i < 8192; i += 256) {          // 8192 float4 = 64x512
    fx4 v = *(const fx4*)(hf + (size_t)gb * 32768 + (size_t)i * 4);
    const int row = i >> 7;          // (i*4)>>9
    const int k = (i * 4) & 511;
    float* d = hs + row * 513 + k;
    d[0] = v[0]; d[1] = v[1]; d[2] = v[2]; d[3] = v[3];
  }
  __syncthreads();
  const int r = tid & 63;
  const int cq = tid >> 6;
  const float* hrow = hs + r * 513;
  const int b_ = gb * 64 + r;
#pragma unroll 1
  for (int j = 0; j < 14; ++j) {
    const int cl = cq + 4 * j;
    if (cl >= 54) break;
    const int C = cg * 54 + cl;      // 0..323
    const float* wp; float bv;
    if (C < 32)       { wp = lin_w + (size_t)C * 512;        bv = lin_b[C]; }
    else if (C < 64)  { wp = lv_w + (size_t)(C - 32) * 512;  bv = lv_b[C - 32]; }
    else if (C < 192) { wp = u_w + (size_t)(C - 64) * 512;   bv = u_b[C - 64]; }
    else if (C < 320) { wp = ww_w + (size_t)(C - 192) * 512; bv = ww_b[C - 192]; }
    else              { wp = bf_w + (size_t)(C - 320) * 512; bv = bf_b[C - 320]; }
    float dot = 0.f;
#pragma unroll 8
    for (int k = 0; k < 512; k += 4) {
      fx4 w = *(const fx4*)(wp + k);
      dot += hrow[k] * w[0] + hrow[k + 1] * w[1] + hrow[k + 2] * w[2] + hrow[k + 3] * w[3];
    }
    const float res = bv + dot;
    if (C < 32)       out[(size_t)b_ * 32 + C] = __builtin_amdgcn_exp2f(res * 1.44269504f) * 0.1f;
    else if (C < 64)  out[32768 + (size_t)b_ * 32 + (C - 32)] = res - 5.f;
    else if (C < 192) out[65536 + (size_t)b_ * 128 + (C - 64)] = res;
    else if (C < 320) out[196608 + (size_t)b_ * 128 + (C - 192)] = res;
    else              out[327680 + (size_t)b_ * 4 + (C - 320)] = res;
  }
}

extern "C" void kernel_launch(void* const* d_in, const int* in_sizes, int n_in,
                              void* d_out, int out_size, void* d_ws, size_t ws_size,
                              hipStream_t stream) {
  (void)in_sizes; (void)n_in; (void)out_size; (void)ws_size;
  const float* x     = (const float*)d_in[0];
  const float* a     = (const float*)d_in[1];
  const float* mask  = (const float*)d_in[2];
  const float* w_ih  = (const float*)d_in[3];
  const float* w_hh  = (const float*)d_in[4];
  const float* b_ih  = (const float*)d_in[5];
  const float* b_hh  = (const float*)d_in[6];
  const float* lin_w = (const float*)d_in[7];
  const float* lin_b = (const float*)d_in[8];
  const float* lv_w  = (const float*)d_in[9];
  const float* lv_b  = (const float*)d_in[10];
  const float* u_w   = (const float*)d_in[11];
  const float* u_b   = (const float*)d_in[12];
  const float* ww_w  = (const float*)d_in[13];
  const float* ww_b  = (const float*)d_in[14];
  const float* bf_w  = (const float*)d_in[15];
  const float* bf_b  = (const float*)d_in[16];

  char* ws = (char*)d_ws;
  short* yw       = (short*)(ws);                 // 33,554,432 B: [256][1024][64] bf16
  short* hbuf     = (short*)(ws + 33554432);      //  2,097,152 B: [2][1024][512] bf16
  float* hfinal   = (float*)(ws + 35651584);      //  2,097,152 B
  unsigned* ctr   = (unsigned*)(ws + 37748736);   //      2,048 B

  hipMemsetAsync(hbuf, 0, 1024 * 512 * 2, stream);   // h(0) = 0
  hipMemsetAsync(ctr, 0, 2048, stream);

  pack_y_kernel<<<1024, 256, 0, stream>>>(x, a, mask, yw);
  lstm_rec<<<256, 256, 0, stream>>>(yw, w_hh, w_ih, b_ih, b_hh, hbuf, hfinal, ctr);
  heads_kernel<<<dim3(16, 6), 256, 0, stream>>>(hfinal, lin_w, lin_b, lv_w, lv_b,
                                                u_w, u_b, ww_w, ww_b, bf_w, bf_b,
                                                (float*)d_out);
}